// Round 10
// baseline (159.961 us; speedup 1.0000x reference)
//
#include <hip/hip_runtime.h>
#include <hip/hip_bf16.h>
#include <math.h>

typedef unsigned short u16;
typedef _Float16 f16x8 __attribute__((ext_vector_type(8)));
typedef float    f32x16 __attribute__((ext_vector_type(16)));
typedef u16      u16x8  __attribute__((ext_vector_type(8)));
typedef u16      u16x4  __attribute__((ext_vector_type(4)));

#define BATCH 16
#define T0 64000
#define T1 32000
#define T2 16000
#define T3 8000
#define NT3 500          // t3 outputs per mega block; 16 blocks x 500 = 8000 exactly
#define NBLKX 16         // 16 x 16 batch = 256 blocks = exactly 1 per CU
#define NROWS1 2064      // local y1 rows staged (1032 LDS lines, incl. guards)

static __device__ __forceinline__ u16 f2h(float f) {
    _Float16 h = (_Float16)f;
    u16 u;
    __builtin_memcpy(&u, &h, 2);
    return u;
}

// ---------------- weight prep (f16, transposed for coalesced A-frag reads) + pooled zero
// a2t[kk][g][o][j]: kk 0..8, g=0..3 (i-granule), o=0..63, j=0..7 (i=8g+j)   18432 u16
// a3t[kk][g][o][j]: kk 0..8, g=0..7,              o=0..127, j=0..7          73728 u16
__global__ __launch_bounds__(256) void prep_w_k(const float* __restrict__ w2,
                                                const float* __restrict__ w3,
                                                u16* __restrict__ a2t,
                                                u16* __restrict__ a3t,
                                                float* __restrict__ pooled) {
    int idx = blockIdx.x * 256 + threadIdx.x;
    if (idx < 18432) {
        int j = idx & 7, o = (idx >> 3) & 63, g = (idx >> 9) & 3, kk = idx >> 11;
        a2t[idx] = f2h(w2[(o * 32 + g * 8 + j) * 9 + kk]);
    } else if (idx < 18432 + 73728) {
        int jdx = idx - 18432;
        int j = jdx & 7, o = (jdx >> 3) & 127, g = (jdx >> 10) & 7, kk = jdx >> 13;
        a3t[jdx] = f2h(w3[(o * 64 + g * 8 + j) * 9 + kk]);
    } else if (idx < 18432 + 73728 + 2048) {
        pooled[idx - 18432 - 73728] = 0.f;
    }
}

// ---------------- mega: conv1(VALU) -> conv2(MFMA, in-place LDS) -> conv3(MFMA)+pool
// block = 512 thr (8 waves), t3 in [r0, r0+500), batch b. LDS: 1032 lines x 128 B.
// Phase A: y1 rows l1 pair-packed 2/line, slot (pp*4+g)^(rr&7); rows 0..2063.
// Phase B chunk cc (512 rows, 2 rows/lane): reads y1 lines <= 512cc+515, then after
// a barrier overwrites lines [512cc, 512cc+511]; chunk 1 reads lines >= 512 -> disjoint.
// Phase C: reads y2 lines 2*nl+kk <= 1030 < 1032; stale lines >= 1024 only reach
// cols nl >= 508 which are masked (nl >= 500) in the epilogue.
// 256 blocks = exactly 1 block/CU (132 KB LDS), 8 waves/block -> 2 waves/SIMD.
__global__ __launch_bounds__(512, 2) void mega_k(const float* __restrict__ audio,
                                                 const float* __restrict__ w1,
                                                 const float* __restrict__ b1,
                                                 const u16* __restrict__ a2t,
                                                 const float* __restrict__ b2,
                                                 const u16* __restrict__ a3t,
                                                 const float* __restrict__ b3,
                                                 float* __restrict__ pooled) {
    __shared__ u16 sm[1032 * 64];          // 132,096 B (<= 160 KB/CU)
    const int tid = threadIdx.x;
    const int b = blockIdx.y;
    const int r0 = blockIdx.x * NT3;
    const int lane = tid & 63, wv = tid >> 6;          // wv 0..7
    const int ls = lane >> 5, ln = lane & 31;

    // ---- Phase A: conv1 into LDS (y1 local rows 0..2063; global t1 = 4*r0-12+l1)
    {
        const float* ar = audio + (size_t)b * T0;
        #pragma unroll
        for (int rep = 0; rep < 5; ++rep) {
            int l1 = rep * 512 + tid;
            if (l1 >= NROWS1) break;
            int t1 = 4 * r0 - 12 + l1;
            int rr = l1 >> 1, pp = l1 & 1;
            if (t1 < 0 || t1 >= T1) {
                u16x8 z;
                #pragma unroll
                for (int q = 0; q < 8; ++q) z[q] = 0;
                #pragma unroll
                for (int g = 0; g < 4; ++g) {
                    int slot = (pp * 4 + g) ^ (rr & 7);
                    *(u16x8*)(sm + rr * 64 + slot * 8) = z;
                }
            } else {
                int base = 2 * t1 - 4;
                float x[9];
                #pragma unroll
                for (int k = 0; k < 9; ++k) {
                    int t0v = base + k;
                    x[k] = (t0v >= 0 && t0v < T0) ? ar[t0v] : 0.f;
                }
                #pragma unroll
                for (int g = 0; g < 4; ++g) {
                    u16x8 v;
                    #pragma unroll
                    for (int j = 0; j < 8; ++j) {
                        int ch = g * 8 + j;
                        float acc = b1[ch];
                        #pragma unroll
                        for (int k = 0; k < 9; ++k) acc = fmaf(x[k], w1[ch * 9 + k], acc);
                        v[j] = f2h(fmaxf(acc, 0.f));
                    }
                    int slot = (pp * 4 + g) ^ (rr & 7);
                    *(u16x8*)(sm + rr * 64 + slot * 8) = v;
                }
            }
        }
    }
    __syncthreads();

    // ---- Phase B: conv2 in 2 chunks of 512 y2 rows (2 rows per lane), in-place
    for (int cc = 0; cc < 2; ++cc) {
        int nl0 = cc * 512 + 32 * wv + ln;   // lane's first y2 row
        int nl1 = nl0 + 256;                 // lane's second y2 row
        f32x16 acc2[2][2];                   // [mi][row]
        #pragma unroll
        for (int mi = 0; mi < 2; ++mi)
            #pragma unroll
            for (int rr = 0; rr < 2; ++rr)
                #pragma unroll
                for (int q = 0; q < 16; ++q) acc2[mi][rr][q] = 0.f;
        f16x8 bfB[2][2];                     // [row][step]
        #pragma unroll 3
        for (int kk = 0; kk < 9; ++kk) {
            int kh = kk >> 1, pp = kk & 1;
            #pragma unroll
            for (int rr = 0; rr < 2; ++rr) {
                int line = (rr ? nl1 : nl0) + kh;
                #pragma unroll
                for (int step = 0; step < 2; ++step) {
                    int slot = (pp * 4 + 2 * step + ls) ^ (line & 7);
                    bfB[rr][step] = *(const f16x8*)(sm + line * 64 + slot * 8);
                }
            }
            const u16* ap = a2t + kk * 2048;
            #pragma unroll
            for (int step = 0; step < 2; ++step) {
                f16x8 af0 = *(const f16x8*)(ap + (2 * step + ls) * 512 + ln * 8);
                f16x8 af1 = *(const f16x8*)(ap + (2 * step + ls) * 512 + (32 + ln) * 8);
                #pragma unroll
                for (int rr = 0; rr < 2; ++rr) {
                    acc2[0][rr] = __builtin_amdgcn_mfma_f32_32x32x16_f16(af0, bfB[rr][step], acc2[0][rr], 0, 0, 0);
                    acc2[1][rr] = __builtin_amdgcn_mfma_f32_32x32x16_f16(af1, bfB[rr][step], acc2[1][rr], 0, 0, 0);
                }
            }
        }
        __syncthreads();                    // all chunk reads done before overwrite
        #pragma unroll
        for (int rr = 0; rr < 2; ++rr) {
            int l2 = rr ? nl1 : nl0;
            int t2 = 2 * r0 - 4 + l2;
            bool valid = (t2 >= 0) && (t2 < T2);
            #pragma unroll
            for (int mi = 0; mi < 2; ++mi)
                #pragma unroll
                for (int q = 0; q < 4; ++q) {
                    u16x4 v;
                    #pragma unroll
                    for (int d = 0; d < 4; ++d) {
                        int o = 32 * mi + 8 * q + 4 * ls + d;
                        float xv = valid ? fmaxf(acc2[mi][rr][4 * q + d] + b2[o], 0.f) : 0.f;
                        v[d] = f2h(xv);
                    }
                    int gy = 4 * mi + q;
                    int sy = gy ^ ((l2 >> 1) & 7);
                    *(u16x4*)(sm + l2 * 64 + sy * 8 + ls * 4) = v;
                }
        }
        __syncthreads();
    }

    // ---- Phase C: conv3 MFMA + mean-pool (M=128 x N=512; mh=wv&1, nh=wv>>1, ni=4)
    const int mh = wv & 1, nh = wv >> 1;               // mh 0..1, nh 0..3
    f32x16 acc3[2][4];
    #pragma unroll
    for (int mi = 0; mi < 2; ++mi)
        #pragma unroll
        for (int ni = 0; ni < 4; ++ni)
            #pragma unroll
            for (int q = 0; q < 16; ++q) acc3[mi][ni][q] = 0.f;

    f16x8 bf[4][4];
    for (int kk = 0; kk < 9; ++kk) {
        const u16* ap = a3t + kk * 8192;
        #pragma unroll
        for (int ni = 0; ni < 4; ++ni) {
            int nl = 128 * nh + 32 * ni + ln;
            int l2 = 2 * nl + kk;                      // <= 1030 < 1032
            int rrC = nl + (kk >> 1);
            #pragma unroll
            for (int step = 0; step < 4; ++step) {
                int sy = (2 * step + ls) ^ (rrC & 7);
                bf[ni][step] = *(const f16x8*)(sm + l2 * 64 + sy * 8);
            }
        }
        #pragma unroll
        for (int step = 0; step < 4; ++step) {
            f16x8 af0 = *(const f16x8*)(ap + (2 * step + ls) * 1024 + (64 * mh + ln) * 8);
            f16x8 af1 = *(const f16x8*)(ap + (2 * step + ls) * 1024 + (64 * mh + 32 + ln) * 8);
            #pragma unroll
            for (int ni = 0; ni < 4; ++ni) {
                acc3[0][ni] = __builtin_amdgcn_mfma_f32_32x32x16_f16(af0, bf[ni][step], acc3[0][ni], 0, 0, 0);
                acc3[1][ni] = __builtin_amdgcn_mfma_f32_32x32x16_f16(af1, bf[ni][step], acc3[1][ni], 0, 0, 0);
            }
        }
    }

    // epilogue: bias+relu, mask nl>=500, per-wave partials -> LDS reduce -> atomics
    float loc[32];
    #pragma unroll
    for (int mi = 0; mi < 2; ++mi)
        #pragma unroll
        for (int r = 0; r < 16; ++r) {
            int o = 64 * mh + 32 * mi + (r & 3) + 8 * (r >> 2) + 4 * ls;
            float bias = b3[o];
            float s = 0.f;
            #pragma unroll
            for (int ni = 0; ni < 4; ++ni) {
                int nl = 128 * nh + 32 * ni + ln;
                float v = fmaxf(acc3[mi][ni][r] + bias, 0.f);
                s += (nl < NT3) ? v : 0.f;
            }
            loc[mi * 16 + r] = s;
        }
    __syncthreads();
    float* smf = (float*)sm;               // [4 nh][128 o][32 ln] = 64 KB <= 132 KB
    #pragma unroll
    for (int mi = 0; mi < 2; ++mi)
        #pragma unroll
        for (int r = 0; r < 16; ++r) {
            int o = 64 * mh + 32 * mi + (r & 3) + 8 * (r >> 2) + 4 * ls;
            smf[nh * 4096 + o * 32 + ln] = loc[mi * 16 + r];
        }
    __syncthreads();
    if (tid < 128) {
        int o = tid;
        float s = 0.f;
        #pragma unroll
        for (int j = 0; j < 32; ++j) {
            int col = (j + o) & 31;
            s += smf[o * 32 + col] + smf[4096 + o * 32 + col]
               + smf[8192 + o * 32 + col] + smf[12288 + o * 32 + col];
        }
        atomicAdd(&pooled[b * 128 + o], s);
    }
}

// ---------------- fused feats + synthesis
__global__ __launch_bounds__(256) void synth_k(const float* __restrict__ f0,
                                               const float* __restrict__ wn,
                                               const float* __restrict__ pooled,
                                               const float* __restrict__ wl,
                                               const float* __restrict__ bl,
                                               float* __restrict__ out) {
    int tid = threadIdx.x;
    int b = blockIdx.y;
    __shared__ float pl[128];
    __shared__ float red[64];
    __shared__ float sa[64];
    __shared__ float nm[64];
    if (tid < 128) pl[tid] = pooled[b * 128 + tid] * (1.0f / 8000.0f);
    __syncthreads();
    float feat = 0.f;
    if (tid < 128) {
        feat = bl[tid];
        #pragma unroll 8
        for (int i = 0; i < 128; ++i) feat = fmaf(pl[i], wl[tid * 128 + i], feat);
    }
    if (tid < 64) red[tid] = fmaxf(feat, 0.f);
    __syncthreads();
    if (tid < 32) red[tid] += red[tid + 32];
    __syncthreads();
    if (tid < 16) red[tid] += red[tid + 16];
    __syncthreads();
    if (tid < 8) red[tid] += red[tid + 8];
    __syncthreads();
    if (tid < 4) red[tid] += red[tid + 4];
    __syncthreads();
    if (tid < 2) red[tid] += red[tid + 2];
    __syncthreads();
    if (tid == 0) red[0] += red[1];
    __syncthreads();
    float denom = red[0] + 1e-6f;
    if (tid < 64) sa[tid] = fmaxf(feat, 0.f) / denom;
    else if (tid < 128) nm[tid - 64] = feat;
    __syncthreads();
    int t = blockIdx.x * 256 + tid;
    float f0v = f0[(size_t)b * T0 + t];
    // u = f0 * t * 4/63999 (linspace incl endpoint); frac in double, per-harmonic
    // frac(h*uf) exact enough in fp32 since uf in [0,1).
    double u = (double)f0v * ((double)t * (4.0 / 63999.0));
    float uf = (float)(u - floor(u));
    float acc = 0.f;
    #pragma unroll
    for (int h = 1; h <= 64; ++h) {
        float x = uf * (float)h;
        x = x - floorf(x);
        acc = fmaf(sa[h - 1], __builtin_amdgcn_sinf(x), acc);   // sin(2*pi*x)
    }
    out[(size_t)b * T0 + t] = acc + wn[(size_t)b * T0 + t] * nm[t / 1000];
}

extern "C" void kernel_launch(void* const* d_in, const int* in_sizes, int n_in,
                              void* d_out, int out_size, void* d_ws, size_t ws_size,
                              hipStream_t stream) {
    const float* audio = (const float*)d_in[0];
    const float* f0    = (const float*)d_in[1];
    const float* wn    = (const float*)d_in[2];
    const float* w1    = (const float*)d_in[3];
    const float* b1    = (const float*)d_in[4];
    const float* w2    = (const float*)d_in[5];
    const float* b2    = (const float*)d_in[6];
    const float* w3    = (const float*)d_in[7];
    const float* b3    = (const float*)d_in[8];
    const float* wl    = (const float*)d_in[9];
    const float* bl    = (const float*)d_in[10];
    float* out = (float*)d_out;

    char* ws = (char*)d_ws;
    float* pooled = (float*)(ws);                  // 2048 f32 (zeroed by prep_w_k)
    u16* a2t = (u16*)(ws + 8192);                  // 18432 u16
    u16* a3t = (u16*)(ws + 8192 + 36864);          // 73728 u16

    prep_w_k<<<368, 256, 0, stream>>>(w2, w3, a2t, a3t, pooled);
    mega_k<<<dim3(NBLKX, BATCH), 512, 0, stream>>>(audio, w1, b1, a2t, b2, a3t, b3, pooled);
    synth_k<<<dim3(T0 / 256, BATCH), 256, 0, stream>>>(f0, wn, pooled, wl, bl, out);
}